// Round 2
// 1020.369 us; speedup vs baseline: 1.0020x; 1.0020x over previous
//
#include <hip/hip_runtime.h>
#include <math.h>

#define IGNORE_INDEX (-100)
#define N_ROWS 4096
#define VOCAB 50257
#define EPSILON 1e-10

// Branchless online-softmax update for one float4 (5 exps / 4 elems, no divergence).
// Chain-carried deps: m via one fmax, s via one fma — both short; exps are off-chain.
__device__ __forceinline__ void upd4(float4 x, float& m, float& s) {
    float lm = fmaxf(fmaxf(x.x, x.y), fmaxf(x.z, x.w));
    float mn = fmaxf(m, lm);
    float r  = __expf(m - mn);          // == 1.0f when max didn't move
    float e0 = __expf(x.x - mn);
    float e1 = __expf(x.y - mn);
    float e2 = __expf(x.z - mn);
    float e3 = __expf(x.w - mn);
    s = fmaf(s, r, (e0 + e1) + (e2 + e3));
    m = mn;
}

// Branchless scalar update (lead/tail elements only).
__device__ __forceinline__ void upd1(float x, float& m, float& s) {
    float mn = fmaxf(m, x);
    s = fmaf(s, __expf(m - mn), __expf(x - mn));
    m = mn;
}

// Merge two (max, sumexp) pairs (used only in reductions — negligible cost).
__device__ __forceinline__ void merge(float& m, float& s, float mo, float so) {
    float M = fmaxf(m, mo);
    if (M == -INFINITY) { m = M; s = 0.0f; return; }   // both empty
    s = s * __expf(m - M) + so * __expf(mo - M);
    m = M;
}

__global__ __launch_bounds__(256) void row_lse_kernel(
        const float* __restrict__ pred,
        const int* __restrict__ tgt,
        double* __restrict__ per_row,
        int* __restrict__ valid_flags) {
    const int r   = blockIdx.x;
    const int tid = threadIdx.x;
    const int nt  = blockDim.x;   // 256

    const float* row = pred + (size_t)r * VOCAB;

    // Row start is misaligned: 50257 % 4 == 1, so misalign (elements) = r % 4.
    const int mis  = r & 3;
    const int lead = (4 - mis) & 3;
    const int nv   = (VOCAB - lead) >> 2;           // # of aligned float4
    const int tail = VOCAB - lead - (nv << 2);

    // 4 independent accumulator chains for ILP.
    float m0 = -INFINITY, m1 = -INFINITY, m2 = -INFINITY, m3 = -INFINITY;
    float s0 = 0.f, s1 = 0.f, s2 = 0.f, s3 = 0.f;

    const float4* v = (const float4*)(row + lead);

    // Main loop: 4 float4 per thread-iteration; loads issued back-to-back so the
    // compiler keeps >=4 global_load_dwordx4 in flight per wave (latency hiding).
    int i = tid;
    for (; i + 3 * nt < nv; i += 4 * nt) {
        float4 a = v[i];
        float4 b = v[i + nt];
        float4 c = v[i + 2 * nt];
        float4 d = v[i + 3 * nt];
        upd4(a, m0, s0);
        upd4(b, m1, s1);
        upd4(c, m2, s2);
        upd4(d, m3, s3);
    }
    // Remainder float4s (< 4*nt of them).
    for (; i < nv; i += nt) upd4(v[i], m0, s0);

    // lead scalars (0..3 of them)
    for (int j = tid; j < lead; j += nt) upd1(row[j], m1, s1);
    // tail scalars (0..3 of them)
    {
        const float* tp = row + lead + (nv << 2);
        for (int j = tid; j < tail; j += nt) upd1(tp[j], m2, s2);
    }

    // Fold 4 chains into one (m0, s0).
    merge(m0, s0, m1, s1);
    merge(m0, s0, m2, s2);
    merge(m0, s0, m3, s3);

    // Wave (64-lane) butterfly reduction.
    #pragma unroll
    for (int off = 32; off > 0; off >>= 1) {
        float mo = __shfl_xor(m0, off);
        float so = __shfl_xor(s0, off);
        merge(m0, s0, mo, so);
    }

    // Cross-wave via LDS (4 waves of 64).
    __shared__ float sm[4];
    __shared__ float ss[4];
    const int wave = tid >> 6;
    if ((tid & 63) == 0) { sm[wave] = m0; ss[wave] = s0; }
    __syncthreads();

    if (tid == 0) {
        float M = sm[0], S = ss[0];
        merge(M, S, sm[1], ss[1]);
        merge(M, S, sm[2], ss[2]);
        merge(M, S, sm[3], ss[3]);

        const int t     = tgt[r];
        const bool ok   = (t != IGNORE_INDEX);
        const int  st   = min(max(t, 0), VOCAB - 1);
        const float tl  = row[st];

        // prob = exp(tl - logZ) = exp(tl - M) / S   (epilogue in fp64, cheap)
        const double prob = exp((double)tl - (double)M) / (double)S;
        const double pr   = log(1.0 - prob + EPSILON);

        per_row[r]     = ok ? pr : 0.0;
        valid_flags[r] = ok ? 1 : 0;
    }
}

__global__ __launch_bounds__(256) void final_reduce_kernel(
        const double* __restrict__ per_row,
        const int* __restrict__ valid_flags,
        float* __restrict__ out) {
    double sum = 0.0;
    int    cnt = 0;
    for (int i = threadIdx.x; i < N_ROWS; i += 256) {
        sum += per_row[i];
        cnt += valid_flags[i];
    }
    #pragma unroll
    for (int off = 32; off > 0; off >>= 1) {
        sum += __shfl_xor(sum, off);
        cnt += __shfl_xor(cnt, off);
    }
    __shared__ double sd[4];
    __shared__ int    sc[4];
    const int wave = threadIdx.x >> 6;
    if ((threadIdx.x & 63) == 0) { sd[wave] = sum; sc[wave] = cnt; }
    __syncthreads();
    if (threadIdx.x == 0) {
        double total = sd[0] + sd[1] + sd[2] + sd[3];
        int    c     = sc[0] + sc[1] + sc[2] + sc[3];
        if (c < 1) c = 1;
        out[0] = (float)(-total / (double)c);
    }
}

extern "C" void kernel_launch(void* const* d_in, const int* in_sizes, int n_in,
                              void* d_out, int out_size, void* d_ws, size_t ws_size,
                              hipStream_t stream) {
    const float* pred = (const float*)d_in[0];
    const int*   tgt  = (const int*)d_in[1];

    double* per_row     = (double*)d_ws;
    int*    valid_flags = (int*)((char*)d_ws + (size_t)N_ROWS * sizeof(double));

    row_lse_kernel<<<N_ROWS, 256, 0, stream>>>(pred, tgt, per_row, valid_flags);
    final_reduce_kernel<<<1, 256, 0, stream>>>(per_row, valid_flags, (float*)d_out);
}